// Round 1
// baseline (1346.330 us; speedup 1.0000x reference)
//
#include <hip/hip_runtime.h>

#define NN 100000
#define NE 1600000
#define DD 64
#define NL 4
#define DT 32

// ---------------- CSR build ----------------

__global__ __launch_bounds__(256) void count_kernel(const int* __restrict__ dst,
                                                    int* __restrict__ cnt) {
  int e = blockIdx.x * 256 + threadIdx.x;
  atomicAdd(&cnt[dst[e]], 1);
}

__global__ __launch_bounds__(1024) void scan_kernel(const int* __restrict__ cnt,
                                                    int* __restrict__ row_ptr,
                                                    int* __restrict__ cursor,
                                                    float* __restrict__ deg_inv) {
  __shared__ int part[1024];
  const int n = NN;
  int t = threadIdx.x;
  int chunk = (n + 1023) >> 10;  // 98
  int b = t * chunk;
  int e = min(b + chunk, n);
  int s = 0;
  for (int i = b; i < e; ++i) s += cnt[i];
  part[t] = s;
  __syncthreads();
  for (int off = 1; off < 1024; off <<= 1) {
    int v = (t >= off) ? part[t - off] : 0;
    __syncthreads();
    part[t] += v;
    __syncthreads();
  }
  int run = (t == 0) ? 0 : part[t - 1];
  for (int i = b; i < e; ++i) {
    int c = cnt[i];
    row_ptr[i] = run;
    cursor[i] = run;
    deg_inv[i] = 1.0f / (float)(c > 1 ? c : 1);
    run += c;
  }
  if (t == 1023) row_ptr[n] = part[1023];
}

__global__ __launch_bounds__(256) void fill_kernel(const int* __restrict__ src,
                                                   const int* __restrict__ dst,
                                                   int* __restrict__ cursor,
                                                   int* __restrict__ col) {
  int e = blockIdx.x * 256 + threadIdx.x;
  int pos = atomicAdd(&cursor[dst[e]], 1);
  col[pos] = src[e];
}

// ---------------- mean aggregation: one wave per node, lane = feature ----------------

__global__ __launch_bounds__(256) void agg_kernel(const float* __restrict__ h,
                                                  const int* __restrict__ row_ptr,
                                                  const int* __restrict__ col,
                                                  const float* __restrict__ deg_inv,
                                                  float* __restrict__ agg) {
  int w = (int)((blockIdx.x * 256u + threadIdx.x) >> 6);
  int lane = threadIdx.x & 63;
  if (w >= NN) return;
  int beg = __builtin_amdgcn_readfirstlane(row_ptr[w]);
  int end = __builtin_amdgcn_readfirstlane(row_ptr[w + 1]);
  float acc = 0.f;
  for (int e = beg; e < end; ++e) {
    int s = __builtin_amdgcn_readfirstlane(col[e]);
    acc += h[(size_t)s * DD + lane];
  }
  agg[(size_t)w * DD + lane] = acc * deg_inv[w];
}

// ---------------- layer GEMM: hn = agg@Wl + bl + h@Wr ----------------
// 64-node x 64-col tile per block of 128 threads; each thread 4 nodes x 8 cols.
// Wl/Wr staged in two 32-row phases (fits 64KB LDS with +1-padded a/h tiles).

__global__ __launch_bounds__(128) void layer_kernel(const float* __restrict__ agg,
                                                    const float* __restrict__ h,
                                                    const float* __restrict__ Wl,
                                                    const float* __restrict__ bl,
                                                    const float* __restrict__ Wr,
                                                    float* __restrict__ hn) {
  __shared__ float WlS[32 * 64];
  __shared__ float WrS[32 * 64];
  __shared__ float aS[64][65];
  __shared__ float hS[64][65];
  int tid = threadIdx.x;
  int base = blockIdx.x * 64;

  // stage agg/h rows for 64 nodes (scalar LDS writes: padded rows break f4 alignment)
#pragma unroll
  for (int j = 0; j < 8; ++j) {
    int idx = tid + j * 128;          // float4 index 0..1023
    int r = idx >> 4;
    int c4 = (idx & 15) << 2;
    int node = base + r;
    float4 av = make_float4(0.f, 0.f, 0.f, 0.f), hv = av;
    if (node < NN) {
      av = *(const float4*)(agg + (size_t)node * 64 + c4);
      hv = *(const float4*)(h + (size_t)node * 64 + c4);
    }
    aS[r][c4 + 0] = av.x; aS[r][c4 + 1] = av.y; aS[r][c4 + 2] = av.z; aS[r][c4 + 3] = av.w;
    hS[r][c4 + 0] = hv.x; hS[r][c4 + 1] = hv.y; hS[r][c4 + 2] = hv.z; hS[r][c4 + 3] = hv.w;
  }

  int tx = tid & 7, ty = tid >> 3;
  int m0 = ty * 4, c0 = tx * 8;
  float acc[4][8];
  float4 b0 = *(const float4*)(bl + c0);
  float4 b1 = *(const float4*)(bl + c0 + 4);
#pragma unroll
  for (int m = 0; m < 4; ++m) {
    acc[m][0] = b0.x; acc[m][1] = b0.y; acc[m][2] = b0.z; acc[m][3] = b0.w;
    acc[m][4] = b1.x; acc[m][5] = b1.y; acc[m][6] = b1.z; acc[m][7] = b1.w;
  }

  for (int p = 0; p < 2; ++p) {
    __syncthreads();
#pragma unroll
    for (int j = 0; j < 4; ++j) {
      int idx = tid + j * 128;        // float4 index 0..511
      ((float4*)WlS)[idx] = ((const float4*)(Wl + p * 32 * 64))[idx];
      ((float4*)WrS)[idx] = ((const float4*)(Wr + p * 32 * 64))[idx];
    }
    __syncthreads();
#pragma unroll 8
    for (int k = 0; k < 32; ++k) {
      int kg = p * 32 + k;
      float4 l0 = *(const float4*)&WlS[k * 64 + c0];
      float4 l1 = *(const float4*)&WlS[k * 64 + c0 + 4];
      float4 r0 = *(const float4*)&WrS[k * 64 + c0];
      float4 r1 = *(const float4*)&WrS[k * 64 + c0 + 4];
#pragma unroll
      for (int m = 0; m < 4; ++m) {
        float a = aS[m0 + m][kg];
        float hh = hS[m0 + m][kg];
        acc[m][0] += a * l0.x + hh * r0.x;
        acc[m][1] += a * l0.y + hh * r0.y;
        acc[m][2] += a * l0.z + hh * r0.z;
        acc[m][3] += a * l0.w + hh * r0.w;
        acc[m][4] += a * l1.x + hh * r1.x;
        acc[m][5] += a * l1.y + hh * r1.y;
        acc[m][6] += a * l1.z + hh * r1.z;
        acc[m][7] += a * l1.w + hh * r1.w;
      }
    }
  }

#pragma unroll
  for (int m = 0; m < 4; ++m) {
    int node = base + m0 + m;
    if (node < NN) {
      *(float4*)(hn + (size_t)node * 64 + c0) =
          make_float4(acc[m][0], acc[m][1], acc[m][2], acc[m][3]);
      *(float4*)(hn + (size_t)node * 64 + c0 + 4) =
          make_float4(acc[m][4], acc[m][5], acc[m][6], acc[m][7]);
    }
  }
}

// ---------------- projection: out (+)= h_l @ Wp_l (+ bp on layer 0) ----------------

__global__ __launch_bounds__(256) void proj_kernel(const float* __restrict__ h,
                                                   const float* __restrict__ Wp,
                                                   const float* __restrict__ bp,
                                                   float* __restrict__ out, int layer0) {
  __shared__ float WpS[64 * 32];
  int tid = threadIdx.x;
#pragma unroll
  for (int j = 0; j < 8; ++j) WpS[tid + j * 256] = Wp[tid + j * 256];
  __syncthreads();
  int lane = tid & 63;
  int c = lane & 31;
  int node = blockIdx.x * 8 + (tid >> 5);
  if (node >= NN) return;
  const float* hr = h + (size_t)node * 64;
  float h0 = hr[c], h1 = hr[32 + c];
  float acc = layer0 ? bp[c] : out[(size_t)node * 32 + c];
#pragma unroll 8
  for (int k = 0; k < 32; ++k) {
    float a = __shfl(h0, (lane & 32) | k, 64);
    float b = __shfl(h1, (lane & 32) | k, 64);
    acc += a * WpS[k * 32 + c] + b * WpS[(k + 32) * 32 + c];
  }
  out[(size_t)node * 32 + c] = acc;
}

// ---------------- launch ----------------

extern "C" void kernel_launch(void* const* d_in, const int* in_sizes, int n_in,
                              void* d_out, int out_size, void* d_ws, size_t ws_size,
                              hipStream_t stream) {
  const float* x  = (const float*)d_in[0];
  const int*   ei = (const int*)d_in[1];   // [2, NE] int32
  const float* Wl = (const float*)d_in[2];
  const float* bl = (const float*)d_in[3];
  const float* Wr = (const float*)d_in[4];
  const float* Wp = (const float*)d_in[5];
  const float* bp = (const float*)d_in[6];
  float* out = (float*)d_out;

  char* ws = (char*)d_ws;
  size_t off = 0;
  auto alloc = [&](size_t bytes) {
    void* p = ws + off;
    off = (off + bytes + 255) & ~(size_t)255;
    return p;
  };
  int*   cnt     = (int*)alloc((size_t)NN * 4);
  int*   row_ptr = (int*)alloc(((size_t)NN + 1) * 4);
  int*   cursor  = (int*)alloc((size_t)NN * 4);
  float* deginv  = (float*)alloc((size_t)NN * 4);
  int*   col     = (int*)alloc((size_t)NE * 4);
  float* agg     = (float*)alloc((size_t)NN * 64 * 4);
  float* hA      = (float*)alloc((size_t)NN * 64 * 4);
  float* hB      = (float*)alloc((size_t)NN * 64 * 4);

  hipMemsetAsync(cnt, 0, (size_t)NN * 4, stream);
  count_kernel<<<NE / 256, 256, 0, stream>>>(ei + NE, cnt);
  scan_kernel<<<1, 1024, 0, stream>>>(cnt, row_ptr, cursor, deginv);
  fill_kernel<<<NE / 256, 256, 0, stream>>>(ei, ei + NE, cursor, col);

  const float* cur = x;
  float* bufs[2] = {hA, hB};
  for (int l = 0; l < NL; ++l) {
    agg_kernel<<<NN / 4, 256, 0, stream>>>(cur, row_ptr, col, deginv, agg);
    float* nxt = bufs[l & 1];
    layer_kernel<<<(NN + 63) / 64, 128, 0, stream>>>(
        agg, cur, Wl + l * 64 * 64, bl + l * 64, Wr + l * 64 * 64, nxt);
    proj_kernel<<<(NN + 7) / 8, 256, 0, stream>>>(nxt, Wp + l * 64 * 32, bp, out,
                                                  l == 0 ? 1 : 0);
    cur = nxt;
  }
}

// Round 2
// 1085.346 us; speedup vs baseline: 1.2405x; 1.2405x over previous
//
#include <hip/hip_runtime.h>

#define NN 100000
#define NE 1600000
#define DD 64
#define NL 4
#define DT 32

#define SCAN_TILE 1024
#define NTILES ((NN + SCAN_TILE - 1) / SCAN_TILE)  // 98

// ---------------- CSR build ----------------

__global__ __launch_bounds__(256) void count_kernel(const int* __restrict__ dst,
                                                    int* __restrict__ cnt) {
  int e = blockIdx.x * 256 + threadIdx.x;
  atomicAdd(&cnt[dst[e]], 1);
}

// A: per-tile reduce (1024 cnts per block)
__global__ __launch_bounds__(256) void scan_reduce(const int* __restrict__ cnt,
                                                   int* __restrict__ tile_sum) {
  __shared__ int ws[4];
  int t = threadIdx.x;
  int base = blockIdx.x * SCAN_TILE + t * 4;
  int s = 0;
#pragma unroll
  for (int i = 0; i < 4; ++i) {
    int idx = base + i;
    if (idx < NN) s += cnt[idx];
  }
#pragma unroll
  for (int off = 32; off; off >>= 1) s += __shfl_down(s, off, 64);
  if ((t & 63) == 0) ws[t >> 6] = s;
  __syncthreads();
  if (t == 0) tile_sum[blockIdx.x] = ws[0] + ws[1] + ws[2] + ws[3];
}

// B: scan the 98 tile sums (single tiny block)
__global__ __launch_bounds__(128) void scan_tiles(const int* __restrict__ tile_sum,
                                                  int* __restrict__ tile_off,
                                                  int* __restrict__ row_ptr) {
  __shared__ int part[128];
  int t = threadIdx.x;
  int v = (t < NTILES) ? tile_sum[t] : 0;
  part[t] = v;
  __syncthreads();
  for (int off = 1; off < 128; off <<= 1) {
    int u = (t >= off) ? part[t - off] : 0;
    __syncthreads();
    part[t] += u;
    __syncthreads();
  }
  if (t < NTILES) tile_off[t] = part[t] - v;
  if (t == 127) row_ptr[NN] = part[127];
}

// C: per-tile apply — block scan + write row_ptr/cursor/deg_inv
__global__ __launch_bounds__(256) void scan_apply(const int* __restrict__ cnt,
                                                  const int* __restrict__ tile_off,
                                                  int* __restrict__ row_ptr,
                                                  int* __restrict__ cursor,
                                                  float* __restrict__ deg_inv) {
  __shared__ int part[256];
  int t = threadIdx.x;
  int base = blockIdx.x * SCAN_TILE + t * 4;
  int c[4];
#pragma unroll
  for (int i = 0; i < 4; ++i) {
    int idx = base + i;
    c[i] = (idx < NN) ? cnt[idx] : 0;
  }
  int s = c[0] + c[1] + c[2] + c[3];
  part[t] = s;
  __syncthreads();
  for (int off = 1; off < 256; off <<= 1) {
    int u = (t >= off) ? part[t - off] : 0;
    __syncthreads();
    part[t] += u;
    __syncthreads();
  }
  int run = tile_off[blockIdx.x] + part[t] - s;
#pragma unroll
  for (int i = 0; i < 4; ++i) {
    int idx = base + i;
    if (idx < NN) {
      row_ptr[idx] = run;
      cursor[idx] = run;
      deg_inv[idx] = 1.0f / (float)(c[i] > 1 ? c[i] : 1);
      run += c[i];
    }
  }
}

__global__ __launch_bounds__(256) void fill_kernel(const int* __restrict__ src,
                                                   const int* __restrict__ dst,
                                                   int* __restrict__ cursor,
                                                   int* __restrict__ col) {
  int e = blockIdx.x * 256 + threadIdx.x;
  int pos = atomicAdd(&cursor[dst[e]], 1);
  col[pos] = src[e];
}

// ---------------- mean aggregation: one wave per node, lane = feature ----------------

__global__ __launch_bounds__(256) void agg_kernel(const float* __restrict__ h,
                                                  const int* __restrict__ row_ptr,
                                                  const int* __restrict__ col,
                                                  const float* __restrict__ deg_inv,
                                                  float* __restrict__ agg) {
  int w = (int)((blockIdx.x * 256u + threadIdx.x) >> 6);
  int lane = threadIdx.x & 63;
  if (w >= NN) return;
  int beg = __builtin_amdgcn_readfirstlane(row_ptr[w]);
  int end = __builtin_amdgcn_readfirstlane(row_ptr[w + 1]);
  float acc = 0.f;
  for (int e = beg; e < end; ++e) {
    int s = __builtin_amdgcn_readfirstlane(col[e]);
    acc += h[(size_t)s * DD + lane];
  }
  agg[(size_t)w * DD + lane] = acc * deg_inv[w];
}

// ---------------- layer GEMM: hn = agg@Wl + bl + h@Wr ----------------

__global__ __launch_bounds__(128) void layer_kernel(const float* __restrict__ agg,
                                                    const float* __restrict__ h,
                                                    const float* __restrict__ Wl,
                                                    const float* __restrict__ bl,
                                                    const float* __restrict__ Wr,
                                                    float* __restrict__ hn) {
  __shared__ float WlS[32 * 64];
  __shared__ float WrS[32 * 64];
  __shared__ float aS[64][65];
  __shared__ float hS[64][65];
  int tid = threadIdx.x;
  int base = blockIdx.x * 64;

#pragma unroll
  for (int j = 0; j < 8; ++j) {
    int idx = tid + j * 128;          // float4 index 0..1023
    int r = idx >> 4;
    int c4 = (idx & 15) << 2;
    int node = base + r;
    float4 av = make_float4(0.f, 0.f, 0.f, 0.f), hv = av;
    if (node < NN) {
      av = *(const float4*)(agg + (size_t)node * 64 + c4);
      hv = *(const float4*)(h + (size_t)node * 64 + c4);
    }
    aS[r][c4 + 0] = av.x; aS[r][c4 + 1] = av.y; aS[r][c4 + 2] = av.z; aS[r][c4 + 3] = av.w;
    hS[r][c4 + 0] = hv.x; hS[r][c4 + 1] = hv.y; hS[r][c4 + 2] = hv.z; hS[r][c4 + 3] = hv.w;
  }

  int tx = tid & 7, ty = tid >> 3;
  int m0 = ty * 4, c0 = tx * 8;
  float acc[4][8];
  float4 b0 = *(const float4*)(bl + c0);
  float4 b1 = *(const float4*)(bl + c0 + 4);
#pragma unroll
  for (int m = 0; m < 4; ++m) {
    acc[m][0] = b0.x; acc[m][1] = b0.y; acc[m][2] = b0.z; acc[m][3] = b0.w;
    acc[m][4] = b1.x; acc[m][5] = b1.y; acc[m][6] = b1.z; acc[m][7] = b1.w;
  }

  for (int p = 0; p < 2; ++p) {
    __syncthreads();
#pragma unroll
    for (int j = 0; j < 4; ++j) {
      int idx = tid + j * 128;        // float4 index 0..511
      ((float4*)WlS)[idx] = ((const float4*)(Wl + p * 32 * 64))[idx];
      ((float4*)WrS)[idx] = ((const float4*)(Wr + p * 32 * 64))[idx];
    }
    __syncthreads();
#pragma unroll 8
    for (int k = 0; k < 32; ++k) {
      int kg = p * 32 + k;
      float4 l0 = *(const float4*)&WlS[k * 64 + c0];
      float4 l1 = *(const float4*)&WlS[k * 64 + c0 + 4];
      float4 r0 = *(const float4*)&WrS[k * 64 + c0];
      float4 r1 = *(const float4*)&WrS[k * 64 + c0 + 4];
#pragma unroll
      for (int m = 0; m < 4; ++m) {
        float a = aS[m0 + m][kg];
        float hh = hS[m0 + m][kg];
        acc[m][0] += a * l0.x + hh * r0.x;
        acc[m][1] += a * l0.y + hh * r0.y;
        acc[m][2] += a * l0.z + hh * r0.z;
        acc[m][3] += a * l0.w + hh * r0.w;
        acc[m][4] += a * l1.x + hh * r1.x;
        acc[m][5] += a * l1.y + hh * r1.y;
        acc[m][6] += a * l1.z + hh * r1.z;
        acc[m][7] += a * l1.w + hh * r1.w;
      }
    }
  }

#pragma unroll
  for (int m = 0; m < 4; ++m) {
    int node = base + m0 + m;
    if (node < NN) {
      *(float4*)(hn + (size_t)node * 64 + c0) =
          make_float4(acc[m][0], acc[m][1], acc[m][2], acc[m][3]);
      *(float4*)(hn + (size_t)node * 64 + c0 + 4) =
          make_float4(acc[m][4], acc[m][5], acc[m][6], acc[m][7]);
    }
  }
}

// ---------------- projection: out (+)= h_l @ Wp_l (+ bp on layer 0) ----------------

__global__ __launch_bounds__(256) void proj_kernel(const float* __restrict__ h,
                                                   const float* __restrict__ Wp,
                                                   const float* __restrict__ bp,
                                                   float* __restrict__ out, int layer0) {
  __shared__ float WpS[64 * 32];
  int tid = threadIdx.x;
#pragma unroll
  for (int j = 0; j < 8; ++j) WpS[tid + j * 256] = Wp[tid + j * 256];
  __syncthreads();
  int lane = tid & 63;
  int c = lane & 31;
  int node = blockIdx.x * 8 + (tid >> 5);
  if (node >= NN) return;
  const float* hr = h + (size_t)node * 64;
  float h0 = hr[c], h1 = hr[32 + c];
  float acc = layer0 ? bp[c] : out[(size_t)node * 32 + c];
#pragma unroll 8
  for (int k = 0; k < 32; ++k) {
    float a = __shfl(h0, (lane & 32) | k, 64);
    float b = __shfl(h1, (lane & 32) | k, 64);
    acc += a * WpS[k * 32 + c] + b * WpS[(k + 32) * 32 + c];
  }
  out[(size_t)node * 32 + c] = acc;
}

// ---------------- launch ----------------

extern "C" void kernel_launch(void* const* d_in, const int* in_sizes, int n_in,
                              void* d_out, int out_size, void* d_ws, size_t ws_size,
                              hipStream_t stream) {
  const float* x  = (const float*)d_in[0];
  const int*   ei = (const int*)d_in[1];   // [2, NE] int32
  const float* Wl = (const float*)d_in[2];
  const float* bl = (const float*)d_in[3];
  const float* Wr = (const float*)d_in[4];
  const float* Wp = (const float*)d_in[5];
  const float* bp = (const float*)d_in[6];
  float* out = (float*)d_out;

  char* ws = (char*)d_ws;
  size_t off = 0;
  auto alloc = [&](size_t bytes) {
    void* p = ws + off;
    off = (off + bytes + 255) & ~(size_t)255;
    return p;
  };
  int*   cnt      = (int*)alloc((size_t)NN * 4);
  int*   row_ptr  = (int*)alloc(((size_t)NN + 1) * 4);
  int*   cursor   = (int*)alloc((size_t)NN * 4);
  float* deginv   = (float*)alloc((size_t)NN * 4);
  int*   col      = (int*)alloc((size_t)NE * 4);
  int*   tile_sum = (int*)alloc((size_t)NTILES * 4);
  int*   tile_off = (int*)alloc((size_t)NTILES * 4);
  float* agg      = (float*)alloc((size_t)NN * 64 * 4);
  float* hA       = (float*)alloc((size_t)NN * 64 * 4);
  float* hB       = (float*)alloc((size_t)NN * 64 * 4);

  hipMemsetAsync(cnt, 0, (size_t)NN * 4, stream);
  count_kernel<<<NE / 256, 256, 0, stream>>>(ei + NE, cnt);
  scan_reduce<<<NTILES, 256, 0, stream>>>(cnt, tile_sum);
  scan_tiles<<<1, 128, 0, stream>>>(tile_sum, tile_off, row_ptr);
  scan_apply<<<NTILES, 256, 0, stream>>>(cnt, tile_off, row_ptr, cursor, deginv);
  fill_kernel<<<NE / 256, 256, 0, stream>>>(ei, ei + NE, cursor, col);

  const float* cur = x;
  float* bufs[2] = {hA, hB};
  for (int l = 0; l < NL; ++l) {
    agg_kernel<<<NN / 4, 256, 0, stream>>>(cur, row_ptr, col, deginv, agg);
    float* nxt = bufs[l & 1];
    layer_kernel<<<(NN + 63) / 64, 128, 0, stream>>>(
        agg, cur, Wl + l * 64 * 64, bl + l * 64, Wr + l * 64 * 64, nxt);
    proj_kernel<<<(NN + 7) / 8, 256, 0, stream>>>(nxt, Wp + l * 64 * 32, bp, out,
                                                  l == 0 ? 1 : 0);
    cur = nxt;
  }
}